// Round 2
// baseline (461.965 us; speedup 1.0000x reference)
//
#include <hip/hip_runtime.h>
#include <math.h>

// Problem constants (fixed by the reference file).
constexpr int N_NODES = 100000;
constexpr int N_EDGES = 3200000;
constexpr int F_IN    = 512;
constexpr int HID     = 16;   // HIDDEN == N_CLASSES == 16

constexpr int NPAD = 100352;  // N_NODES rounded up (words)

// Binning parameters: bucket = dst >> 8 (256 nodes/bucket)
constexpr int B_BITS = 8;
constexpr int NPB    = 1 << B_BITS;                    // 256 nodes per bucket
constexpr int NBKT   = (N_NODES + NPB - 1) / NPB;      // 391 buckets
constexpr int SBLK   = 512;                            // scatter blocks
constexpr int CHUNK  = N_EDGES / SBLK;                 // 6250 edges/block (exact)
// Capacity-slotted buckets: mean 8192 edges + pad-to-8 (~896 mean), sd ~90.
constexpr int CAP    = 10240;                          // slots per bucket (mult of 8)

typedef float f32x4 __attribute__((ext_vector_type(4)));
typedef float f32x8 __attribute__((ext_vector_type(8)));
typedef unsigned short u16x8 __attribute__((ext_vector_type(8)));
typedef short bfrag8 __attribute__((ext_vector_type(8)));   // 8 bf16 (4 VGPRs)

__device__ __forceinline__ unsigned short f2bf_rne(float f) {
    unsigned int u = __float_as_uint(f);
    u += 0x7FFFu + ((u >> 16) & 1u);   // round-to-nearest-even
    return (unsigned short)(u >> 16);
}
__device__ __forceinline__ float bf2f(unsigned short u) {
    return __uint_as_float((unsigned int)u << 16);
}

// ---------------------------------------------------------------------------
// K0: prep — W1 transpose->bf16, gcur init to slotted bases, sentinel rows = 0.
__global__ __launch_bounds__(256) void prep_kernel(const float* __restrict__ W1,
                                                   unsigned short* __restrict__ w1t,
                                                   int* __restrict__ gcur,
                                                   unsigned short* __restrict__ hh_bf,
                                                   unsigned short* __restrict__ hh2_bf) {
    int i = blockIdx.x * 256 + threadIdx.x;
    if (i < F_IN * HID) {
        int k = i >> 4, n = i & 15;
        w1t[n * F_IN + k] = f2bf_rne(W1[i]);
    }
    if (i < NBKT) gcur[i] = i * CAP;
    if (i < 16) {                       // sentinel row N_NODES reads as zero
        hh_bf [N_NODES * 16 + i] = 0;
        hh2_bf[N_NODES * 16 + i] = 0;
    }
}

// ---------------------------------------------------------------------------
// K1: scatter edges into capacity-slotted bucket array. No LDS staging (the
// re-read of dst is L2-hot; dropping 64KB LDS doubles blocks/CU).
// Packed as (local_dst<<24 | src).
__global__ __launch_bounds__(1024) void bin_scatter_kernel(const int* __restrict__ src,
                                                           const int* __restrict__ dst,
                                                           int* __restrict__ gcur,
                                                           unsigned int* __restrict__ binned) {
    __shared__ int cnt[NBKT];
    __shared__ int cur[NBKT];
    const int tid = threadIdx.x;
    for (int t = tid; t < NBKT; t += 1024) cnt[t] = 0;
    __syncthreads();
    const int base = blockIdx.x * CHUNK;
    for (int i = tid; i < CHUNK; i += 1024)
        atomicAdd(&cnt[dst[base + i] >> B_BITS], 1);
    __syncthreads();
    for (int t = tid; t < NBKT; t += 1024)
        cur[t] = cnt[t] ? atomicAdd(&gcur[t], cnt[t]) : 0;
    __syncthreads();
    for (int i = tid; i < CHUNK; i += 1024) {
        int d = dst[base + i];
        int b = d >> B_BITS;
        int pos = atomicAdd(&cur[b], 1);
        binned[pos] = ((unsigned)(d & (NPB - 1)) << 24) | (unsigned)src[base + i];
    }
}

// ---------------------------------------------------------------------------
// K2: one block per bucket: LDS CSR build with per-node 8-alignment padding
// (sentinel src = N_NODES fills pad slots -> pull loops are tail-free and
// csr starts are 32B aligned for int4 pair loads). Emits row2/dinv.
__global__ __launch_bounds__(1024) void csr_bucket_kernel(const unsigned int* __restrict__ binned,
                                                          const int* __restrict__ gcur,
                                                          int2* __restrict__ row2,
                                                          int* __restrict__ csr,
                                                          float* __restrict__ dinv) {
    __shared__ unsigned int eb[CAP];   // 40 KB
    __shared__ int deg[NPB];
    __shared__ int pre[NPB];
    __shared__ int cur[NPB];
    const int tid = threadIdx.x;
    const int b = blockIdx.x;
    const int e0 = b * CAP;
    int ne = gcur[b] - e0;
    if (ne > CAP) ne = CAP;            // safety (statistically impossible)
    if (ne < 0) ne = 0;

    if (tid < NPB) deg[tid] = 0;
    for (int i = tid; i < ne; i += 1024) eb[i] = binned[e0 + i];
    __syncthreads();
    for (int i = tid; i < ne; i += 1024)
        atomicAdd(&deg[eb[i] >> 24], 1);
    __syncthreads();
    if (tid < NPB) pre[tid] = (deg[tid] + 7) & ~7;   // padded degree (mult 8)
    __syncthreads();
    for (int off = 1; off < NPB; off <<= 1) {
        int v = 0;
        if (tid < NPB && tid >= off) v = pre[tid - off];
        __syncthreads();
        if (tid < NPB) pre[tid] += v;
        __syncthreads();
    }
    if (tid < NPB) {
        int excl = (tid == 0) ? 0 : pre[tid - 1];
        int start = e0 + excl;
        cur[tid] = start;
        int node = b * NPB + tid;
        if (node < N_NODES) {
            int pd = (deg[tid] + 7) & ~7;
            row2[node] = make_int2(start, start + pd);
            dinv[node] = rsqrtf((float)deg[tid] + 1.0f);
        }
    }
    __syncthreads();
    for (int i = tid; i < ne; i += 1024) {
        unsigned int v = eb[i];
        int pos = atomicAdd(&cur[v >> 24], 1);
        csr[pos] = (int)(v & 0xFFFFFFu);
    }
    // sentinel fill of pad slots (disjoint range from the scatter above)
    if (tid < NPB) {
        int node = b * NPB + tid;
        if (node < N_NODES) {
            int d = deg[tid];
            int pd = (d + 7) & ~7;
            int s = e0 + ((tid == 0) ? 0 : pre[tid - 1]) + d;
            for (int q = d; q < pd; ++q) csr[s++] = N_NODES;
        }
    }
}

// ---------------------------------------------------------------------------
// K3: GEMM1 via MFMA bf16, NO LDS, NO barrier (unchanged; ~BW-bound on x).
__global__ __launch_bounds__(256) void gemm1_kernel(const float* __restrict__ x,
                                                    const unsigned short* __restrict__ w1t,
                                                    const float* __restrict__ b1,
                                                    const float* __restrict__ dinv,
                                                    unsigned short* __restrict__ hh_bf,
                                                    float* __restrict__ aggs1) {
    const int tid  = threadIdx.x;
    const int lane = tid & 63;
    const int wv   = tid >> 6;
    const int m    = lane & 15;
    const int quad = lane >> 4;
    const int node0 = blockIdx.x * 64 + wv * 16;   // this wave's 16-node tile

    int gm = node0 + m; if (gm >= N_NODES) gm = N_NODES - 1;  // clamp loads
    const float* arow = x + (size_t)gm * F_IN + quad * 8;

    // preload all 16 B-frags (16 KB table, L2-hot)
    bfrag8 bfr[16];
    const unsigned short* wbase = w1t + m * F_IN + quad * 8;
    #pragma unroll
    for (int t = 0; t < 16; ++t)
        bfr[t] = *(const bfrag8*)(wbase + t * 32);

    f32x4 acc = {0.f, 0.f, 0.f, 0.f};
    #pragma unroll 4
    for (int t = 0; t < 16; ++t) {
        float4 lo = *(const float4*)(arow + t * 32);
        float4 hi = *(const float4*)(arow + t * 32 + 4);
        bfrag8 afr;
        afr[0] = (short)f2bf_rne(lo.x); afr[1] = (short)f2bf_rne(lo.y);
        afr[2] = (short)f2bf_rne(lo.z); afr[3] = (short)f2bf_rne(lo.w);
        afr[4] = (short)f2bf_rne(hi.x); afr[5] = (short)f2bf_rne(hi.y);
        afr[6] = (short)f2bf_rne(hi.z); afr[7] = (short)f2bf_rne(hi.w);
        acc = __builtin_amdgcn_mfma_f32_16x16x32_bf16(afr, bfr[t], acc, 0, 0, 0);
    }

    // epilogue: D[row=quad*4+r][col=m] (verified mapping)
    const float b1j = b1[m];
    #pragma unroll
    for (int r = 0; r < 4; ++r) {
        int gn = node0 + quad * 4 + r;
        if (gn < N_NODES) {
            float dv = dinv[gn];
            float hv = acc[r] * dv;
            size_t o = (size_t)gn * 16 + m;
            hh_bf[o] = f2bf_rne(hv);
            aggs1[o] = hv * dv + b1j;
        }
    }
}

// ---------------------------------------------------------------------------
// K4: pull1 + relu + layer2 fused. 2 lanes per node, each owning 8 features.
// Per 8 edges per lane: 2 aligned int4 csr loads + 8 dwordx4 (16B) gathers —
// half the wave-level VMEM instructions of the 4-lane version, 2x the
// in-flight loads per wave.
__global__ __launch_bounds__(256) void pull1_kernel(const unsigned short* __restrict__ hh_bf,
                                                    const float* __restrict__ aggs1,
                                                    const float* __restrict__ dinv,
                                                    const int2* __restrict__ row2,
                                                    const int* __restrict__ csr,
                                                    const float* __restrict__ W2,
                                                    const float* __restrict__ b2,
                                                    unsigned short* __restrict__ hh2_bf,
                                                    float* __restrict__ aggs2) {
    __shared__ f32x4 w2s[64];   // W2 row-major [16][16] as float4[64]
    __shared__ float b2s[16];
    const int tid = threadIdx.x;
    if (tid < 64) w2s[tid] = ((const f32x4*)W2)[tid];
    if (tid < 16) b2s[tid] = b2[tid];
    __syncthreads();

    int t = blockIdx.x * 256 + tid;
    int node = t >> 1;
    int l = t & 1;                      // feature octet: features 8l..8l+7
    if (node >= N_NODES) return;

    int2 re = row2[node];
    int p = re.x, e = re.y;
    const unsigned short* hb = hh_bf + (l << 3);
    f32x8 accA = {0,0,0,0,0,0,0,0}, accB = {0,0,0,0,0,0,0,0};
    for (; p < e; p += 8) {
        int4 sA = *(const int4*)(csr + p);
        int4 sB = *(const int4*)(csr + p + 4);
        u16x8 g0 = *(const u16x8*)(hb + (sA.x << 4));
        u16x8 g1 = *(const u16x8*)(hb + (sA.y << 4));
        u16x8 g2 = *(const u16x8*)(hb + (sA.z << 4));
        u16x8 g3 = *(const u16x8*)(hb + (sA.w << 4));
        u16x8 g4 = *(const u16x8*)(hb + (sB.x << 4));
        u16x8 g5 = *(const u16x8*)(hb + (sB.y << 4));
        u16x8 g6 = *(const u16x8*)(hb + (sB.z << 4));
        u16x8 g7 = *(const u16x8*)(hb + (sB.w << 4));
        #pragma unroll
        for (int c = 0; c < 8; ++c) {
            accA[c] += (bf2f(g0[c]) + bf2f(g1[c])) + (bf2f(g2[c]) + bf2f(g3[c]));
            accB[c] += (bf2f(g4[c]) + bf2f(g5[c])) + (bf2f(g6[c]) + bf2f(g7[c]));
        }
    }
    f32x8 a = accA + accB;
    float dv = dinv[node];
    const f32x4* agp = (const f32x4*)(aggs1 + ((size_t)node << 4) + (l << 3));
    f32x4 bA = agp[0], bB = agp[1];
    float v[8];
    #pragma unroll
    for (int c = 0; c < 4; ++c) v[c]     = fmaxf(bA[c] + dv * a[c],     0.f);
    #pragma unroll
    for (int c = 0; c < 4; ++c) v[c + 4] = fmaxf(bB[c] + dv * a[c + 4], 0.f);

    // h2[8l+d] = sum_k v_node[k] * W2[k][8l+d]; v[c] lives on lane k>>3 at c=k&7
    f32x4 h2a = {0.f,0.f,0.f,0.f}, h2b = {0.f,0.f,0.f,0.f};
    #pragma unroll
    for (int k = 0; k < 16; ++k) {
        float vk = __shfl(v[k & 7], k >> 3, 2);
        h2a += vk * w2s[k * 4 + l * 2];
        h2b += vk * w2s[k * 4 + l * 2 + 1];
    }
    u16x8 hs;
    f32x4 agA, agB;
    #pragma unroll
    for (int c = 0; c < 4; ++c) {
        float hv = h2a[c] * dv;
        hs[c] = f2bf_rne(hv);
        agA[c] = hv * dv + b2s[l * 8 + c];
    }
    #pragma unroll
    for (int c = 0; c < 4; ++c) {
        float hv = h2b[c] * dv;
        hs[c + 4] = f2bf_rne(hv);
        agB[c] = hv * dv + b2s[l * 8 + 4 + c];
    }
    size_t o = ((size_t)node << 4) + (l << 3);
    *(u16x8*)(hh2_bf + o) = hs;
    f32x4* o2 = (f32x4*)(aggs2 + o);
    o2[0] = agA; o2[1] = agB;
}

// ---------------------------------------------------------------------------
// K5: pull2 + log_softmax fused. Same 2-lane gather structure.
__global__ __launch_bounds__(256) void pull2_kernel(const unsigned short* __restrict__ hh2_bf,
                                                    const float* __restrict__ aggs2,
                                                    const float* __restrict__ dinv,
                                                    const int2* __restrict__ row2,
                                                    const int* __restrict__ csr,
                                                    float* __restrict__ out) {
    int t = blockIdx.x * 256 + threadIdx.x;
    int node = t >> 1;
    int l = t & 1;
    if (node >= N_NODES) return;

    int2 re = row2[node];
    int p = re.x, e = re.y;
    const unsigned short* hb = hh2_bf + (l << 3);
    f32x8 accA = {0,0,0,0,0,0,0,0}, accB = {0,0,0,0,0,0,0,0};
    for (; p < e; p += 8) {
        int4 sA = *(const int4*)(csr + p);
        int4 sB = *(const int4*)(csr + p + 4);
        u16x8 g0 = *(const u16x8*)(hb + (sA.x << 4));
        u16x8 g1 = *(const u16x8*)(hb + (sA.y << 4));
        u16x8 g2 = *(const u16x8*)(hb + (sA.z << 4));
        u16x8 g3 = *(const u16x8*)(hb + (sA.w << 4));
        u16x8 g4 = *(const u16x8*)(hb + (sB.x << 4));
        u16x8 g5 = *(const u16x8*)(hb + (sB.y << 4));
        u16x8 g6 = *(const u16x8*)(hb + (sB.z << 4));
        u16x8 g7 = *(const u16x8*)(hb + (sB.w << 4));
        #pragma unroll
        for (int c = 0; c < 8; ++c) {
            accA[c] += (bf2f(g0[c]) + bf2f(g1[c])) + (bf2f(g2[c]) + bf2f(g3[c]));
            accB[c] += (bf2f(g4[c]) + bf2f(g5[c])) + (bf2f(g6[c]) + bf2f(g7[c]));
        }
    }
    f32x8 a = accA + accB;
    float dv = dinv[node];
    const f32x4* agp = (const f32x4*)(aggs2 + ((size_t)node << 4) + (l << 3));
    f32x4 bA = agp[0], bB = agp[1];
    float o8[8];
    #pragma unroll
    for (int c = 0; c < 4; ++c) o8[c]     = bA[c] + dv * a[c];
    #pragma unroll
    for (int c = 0; c < 4; ++c) o8[c + 4] = bB[c] + dv * a[c + 4];

    // log_softmax over the 16 features spread across the 2-lane group
    float m = o8[0];
    #pragma unroll
    for (int c = 1; c < 8; ++c) m = fmaxf(m, o8[c]);
    m = fmaxf(m, __shfl_xor(m, 1));
    float s = 0.f;
    #pragma unroll
    for (int c = 0; c < 8; ++c) s += expf(o8[c] - m);
    s += __shfl_xor(s, 1);
    float ls = m + logf(s);
    f32x4 rA, rB;
    #pragma unroll
    for (int c = 0; c < 4; ++c) { rA[c] = o8[c] - ls; rB[c] = o8[c + 4] - ls; }
    f32x4* op = (f32x4*)(out + ((size_t)node << 4) + (l << 3));
    op[0] = rA; op[1] = rB;
}

// ---------------------------------------------------------------------------
extern "C" void kernel_launch(void* const* d_in, const int* in_sizes, int n_in,
                              void* d_out, int out_size, void* d_ws, size_t ws_size,
                              hipStream_t stream) {
    const float* x    = (const float*)d_in[0];
    const float* W1   = (const float*)d_in[1];
    const float* b1   = (const float*)d_in[2];
    const float* W2   = (const float*)d_in[3];
    const float* b2   = (const float*)d_in[4];
    const int*   ei   = (const int*)d_in[5];
    const int*   src  = ei;             // edge_index[0]
    const int*   dst  = ei + N_EDGES;   // edge_index[1]
    float* out = (float*)d_out;

    // workspace layout (4-byte words); total ~36.5 MB
    constexpr size_t SLOTS    = (size_t)NBKT * CAP;          // 4,003,840
    constexpr size_t OFF_DINV = 512;
    constexpr size_t OFF_ROW2 = 512 + (size_t)NPAD;          // int2[N] = 2*NPAD words
    constexpr size_t OFF_CSR  = 512 + 3 * (size_t)NPAD;
    constexpr size_t OFF_HH   = OFF_CSR + SLOTS;             // (N+1)*16 bf16
    constexpr size_t OFF_AG1  = OFF_HH + 800512;
    constexpr size_t OFF_HH2  = OFF_AG1 + 1600000;
    constexpr size_t OFF_AG2  = OFF_HH2 + 800512;
    constexpr size_t OFF_W1T  = OFF_AG2 + 1600000;

    int*   wsi  = (int*)d_ws;
    float* wsf  = (float*)d_ws;
    int*   gcur  = wsi;
    float* dinv  = wsf + OFF_DINV;
    int2*  row2  = (int2*)(wsi + OFF_ROW2);
    int*   csr   = wsi + OFF_CSR;
    unsigned int* binned = (unsigned int*)csr;   // shared: staged per-bucket in LDS
    unsigned short* hh_bf  = (unsigned short*)(wsi + OFF_HH);
    float*          aggs1  = wsf + OFF_AG1;
    unsigned short* hh2_bf = (unsigned short*)(wsi + OFF_HH2);
    float*          aggs2  = wsf + OFF_AG2;
    unsigned short* w1t    = (unsigned short*)(wsi + OFF_W1T);

    const int MB  = (N_NODES + 63) / 64;         // 1563 (MFMA gemm blocks)
    const int GB2 = (N_NODES * 2 + 255) / 256;   // 782 (pull blocks, 2 lanes/node)

    prep_kernel       <<<32, 256, 0, stream>>>(W1, w1t, gcur, hh_bf, hh2_bf);
    bin_scatter_kernel<<<SBLK, 1024, 0, stream>>>(src, dst, gcur, binned);
    csr_bucket_kernel <<<NBKT, 1024, 0, stream>>>(binned, gcur, row2, csr, dinv);
    gemm1_kernel      <<<MB, 256, 0, stream>>>(x, w1t, b1, dinv, hh_bf, aggs1);
    pull1_kernel      <<<GB2, 256, 0, stream>>>(hh_bf, aggs1, dinv, row2, csr, W2, b2, hh2_bf, aggs2);
    pull2_kernel      <<<GB2, 256, 0, stream>>>(hh2_bf, aggs2, dinv, row2, csr, out);
}

// Round 4
// 451.242 us; speedup vs baseline: 1.0238x; 1.0238x over previous
//
#include <hip/hip_runtime.h>
#include <hip/hip_bf16.h>
#include <math.h>

// Problem constants (fixed by the reference file).
constexpr int N_NODES = 100000;
constexpr int N_EDGES = 3200000;
constexpr int F_IN    = 512;
constexpr int HID     = 16;   // HIDDEN == N_CLASSES == 16

constexpr int NPAD = 100352;  // N_NODES rounded up (words)

// Binning parameters: bucket = dst >> 8 (256 nodes/bucket)
constexpr int B_BITS = 8;
constexpr int NPB    = 1 << B_BITS;                    // 256 nodes per bucket
constexpr int NBKT   = (N_NODES + NPB - 1) / NPB;      // 391 buckets
constexpr int SBLK   = 400;                            // scatter blocks
constexpr int CHUNK  = N_EDGES / SBLK;                 // 8000 edges/block (exact)
// Capacity-slotted buckets: mean 8192 edges + pad-to-4 (~384 mean), sd ~90.
constexpr int CAP    = 10240;                          // slots per bucket (mult of 4)

typedef float f32x4 __attribute__((ext_vector_type(4)));
typedef short bfrag8 __attribute__((ext_vector_type(8)));   // 8 bf16 (4 VGPRs)

__device__ __forceinline__ unsigned short f2bf_rne(float f) {
    unsigned int u = __float_as_uint(f);
    u += 0x7FFFu + ((u >> 16) & 1u);   // round-to-nearest-even
    return (unsigned short)(u >> 16);
}
__device__ __forceinline__ float bf2f(unsigned short u) {
    return __uint_as_float((unsigned int)u << 16);
}

// ---------------------------------------------------------------------------
// K0: prep — W1 transpose->bf16, gcur init to slotted bases, sentinel rows = 0.
__global__ __launch_bounds__(256) void prep_kernel(const float* __restrict__ W1,
                                                   unsigned short* __restrict__ w1t,
                                                   int* __restrict__ gcur,
                                                   unsigned short* __restrict__ hh_bf,
                                                   unsigned short* __restrict__ hh2_bf) {
    int i = blockIdx.x * 256 + threadIdx.x;
    if (i < F_IN * HID) {
        int k = i >> 4, n = i & 15;
        w1t[n * F_IN + k] = f2bf_rne(W1[i]);
    }
    if (i < NBKT) gcur[i] = i * CAP;
    if (i < 16) {                       // sentinel row N_NODES reads as zero
        hh_bf [N_NODES * 16 + i] = 0;
        hh2_bf[N_NODES * 16 + i] = 0;
    }
}

// ---------------------------------------------------------------------------
// K1: scatter edges into capacity-slotted bucket array (LDS-staged: src/dst
// read from HBM exactly once). Packed as (local_dst<<24 | src).
__global__ __launch_bounds__(1024) void bin_scatter_kernel(const int* __restrict__ src,
                                                           const int* __restrict__ dst,
                                                           int* __restrict__ gcur,
                                                           unsigned int* __restrict__ binned) {
    __shared__ int sdst[CHUNK];
    __shared__ int ssrc[CHUNK];
    __shared__ int cnt[NBKT];
    __shared__ int cur[NBKT];
    const int tid = threadIdx.x;
    for (int t = tid; t < NBKT; t += 1024) cnt[t] = 0;
    const int base = blockIdx.x * CHUNK;
    for (int i = tid; i < CHUNK; i += 1024) {
        sdst[i] = dst[base + i];
        ssrc[i] = src[base + i];
    }
    __syncthreads();
    for (int i = tid; i < CHUNK; i += 1024)
        atomicAdd(&cnt[sdst[i] >> B_BITS], 1);
    __syncthreads();
    for (int t = tid; t < NBKT; t += 1024)
        cur[t] = cnt[t] ? atomicAdd(&gcur[t], cnt[t]) : 0;
    __syncthreads();
    for (int i = tid; i < CHUNK; i += 1024) {
        int d = sdst[i];
        int b = d >> B_BITS;
        int pos = atomicAdd(&cur[b], 1);
        binned[pos] = ((unsigned)(d & (NPB - 1)) << 24) | (unsigned)ssrc[i];
    }
}

// ---------------------------------------------------------------------------
// K2: one block per bucket: LDS CSR build with per-node 4-alignment padding
// (sentinel src = N_NODES fills pad slots -> pull loops are tail-free and
// csr starts are 16B aligned). Emits row2/dinv, plus a bucket-local
// degree-sorted node permutation (counting sort over 64 degree bins) so
// pull waves process equal-degree nodes -> near-zero divergence waste.
__global__ __launch_bounds__(1024) void csr_bucket_kernel(const unsigned int* __restrict__ binned,
                                                          const int* __restrict__ gcur,
                                                          int2* __restrict__ row2,
                                                          int* __restrict__ csr,
                                                          float* __restrict__ dinv,
                                                          int* __restrict__ perm) {
    __shared__ unsigned int eb[CAP];   // 40 KB
    __shared__ int deg[NPB];
    __shared__ int pre[NPB];
    __shared__ int cur[NPB];
    __shared__ int hist[64];
    __shared__ int hoff[64];
    __shared__ int hcur[64];
    const int tid = threadIdx.x;
    const int b = blockIdx.x;
    const int e0 = b * CAP;
    int ne = gcur[b] - e0;
    if (ne > CAP) ne = CAP;            // safety (statistically impossible)
    if (ne < 0) ne = 0;

    if (tid < NPB) deg[tid] = 0;
    if (tid < 64) hist[tid] = 0;
    for (int i = tid; i < ne; i += 1024) eb[i] = binned[e0 + i];
    __syncthreads();
    for (int i = tid; i < ne; i += 1024)
        atomicAdd(&deg[eb[i] >> 24], 1);
    __syncthreads();
    int pd = 0;
    if (tid < NPB) {
        pd = (deg[tid] + 3) & ~3;      // padded degree (mult 4)
        pre[tid] = pd;
        atomicAdd(&hist[min(pd >> 2, 63)], 1);
    }
    __syncthreads();
    // prefix scan of padded degrees (csr starts)
    for (int off = 1; off < NPB; off <<= 1) {
        int v = 0;
        if (tid < NPB && tid >= off) v = pre[tid - off];
        __syncthreads();
        if (tid < NPB) pre[tid] += v;
        __syncthreads();
    }
    // prefix scan of degree-bin histogram (sort offsets)
    if (tid < 64) hoff[tid] = hist[tid];
    __syncthreads();
    for (int off = 1; off < 64; off <<= 1) {
        int v = 0;
        if (tid < 64 && tid >= off) v = hoff[tid - off];
        __syncthreads();
        if (tid < 64) hoff[tid] += v;
        __syncthreads();
    }
    if (tid < 64) hcur[tid] = (tid == 0) ? 0 : hoff[tid - 1];
    __syncthreads();
    if (tid < NPB) {
        int excl = (tid == 0) ? 0 : pre[tid - 1];
        int start = e0 + excl;
        cur[tid] = start;
        int node = b * NPB + tid;
        if (node < N_NODES) {
            row2[node] = make_int2(start, start + pd);
            dinv[node] = rsqrtf((float)deg[tid] + 1.0f);
        }
        int rank = atomicAdd(&hcur[min(pd >> 2, 63)], 1);
        perm[b * NPB + rank] = node;   // includes tail dummies (node>=N) in bin 0
    }
    __syncthreads();
    for (int i = tid; i < ne; i += 1024) {
        unsigned int v = eb[i];
        int pos = atomicAdd(&cur[v >> 24], 1);
        csr[pos] = (int)(v & 0xFFFFFFu);
    }
    // sentinel fill of pad slots (disjoint range from the scatter above)
    if (tid < NPB) {
        int node = b * NPB + tid;
        if (node < N_NODES) {
            int d = deg[tid];
            int pdl = (d + 3) & ~3;
            int s = e0 + ((tid == 0) ? 0 : pre[tid - 1]) + d;
            for (int q = d; q < pdl; ++q) csr[s++] = N_NODES;
        }
    }
}

// ---------------------------------------------------------------------------
// K3: GEMM1 via MFMA bf16, NO LDS, NO barrier. fp32->bf16 via paired
// __float22bfloat162_rn (v_cvt_pk_bf16_f32: 1 instr / 2 elems, ~8x fewer
// VALU ops than the bit-twiddle; identical RNE bits) -> memory-bound on x.
__global__ __launch_bounds__(256) void gemm1_kernel(const float* __restrict__ x,
                                                    const unsigned short* __restrict__ w1t,
                                                    const float* __restrict__ b1,
                                                    const float* __restrict__ dinv,
                                                    unsigned short* __restrict__ hh_bf,
                                                    float* __restrict__ aggs1) {
    const int tid  = threadIdx.x;
    const int lane = tid & 63;
    const int wv   = tid >> 6;
    const int m    = lane & 15;
    const int quad = lane >> 4;
    const int node0 = blockIdx.x * 64 + wv * 16;   // this wave's 16-node tile

    int gm = node0 + m; if (gm >= N_NODES) gm = N_NODES - 1;  // clamp loads
    const float* arow = x + (size_t)gm * F_IN + quad * 8;

    // preload all 16 B-frags (16 KB table, L2-hot)
    bfrag8 bfr[16];
    const unsigned short* wbase = w1t + m * F_IN + quad * 8;
    #pragma unroll
    for (int t = 0; t < 16; ++t)
        bfr[t] = *(const bfrag8*)(wbase + t * 32);

    f32x4 acc = {0.f, 0.f, 0.f, 0.f};
    #pragma unroll 4
    for (int t = 0; t < 16; ++t) {
        float4 lo = *(const float4*)(arow + t * 32);
        float4 hi = *(const float4*)(arow + t * 32 + 4);
        union { bfrag8 fr; __hip_bfloat162 h2[4]; } u;
        u.h2[0] = __float22bfloat162_rn(float2{lo.x, lo.y});
        u.h2[1] = __float22bfloat162_rn(float2{lo.z, lo.w});
        u.h2[2] = __float22bfloat162_rn(float2{hi.x, hi.y});
        u.h2[3] = __float22bfloat162_rn(float2{hi.z, hi.w});
        acc = __builtin_amdgcn_mfma_f32_16x16x32_bf16(u.fr, bfr[t], acc, 0, 0, 0);
    }

    // epilogue: D[row=quad*4+r][col=m] (verified mapping)
    const float b1j = b1[m];
    #pragma unroll
    for (int r = 0; r < 4; ++r) {
        int gn = node0 + quad * 4 + r;
        if (gn < N_NODES) {
            float dv = dinv[gn];
            float hv = acc[r] * dv;
            size_t o = (size_t)gn * 16 + m;
            hh_bf[o] = f2bf_rne(hv);
            aggs1[o] = hv * dv + b1j;
        }
    }
}

// ---------------------------------------------------------------------------
// K4: pull1 + relu + layer2 fused. 4 lanes per node (degree-sorted order),
// each owning 4 features. Per 4 edges: one aligned int4 csr load + four
// dwordx2 (ushort4) gathers per lane.
__global__ __launch_bounds__(256) void pull1_kernel(const unsigned short* __restrict__ hh_bf,
                                                    const float* __restrict__ aggs1,
                                                    const float* __restrict__ dinv,
                                                    const int2* __restrict__ row2,
                                                    const int* __restrict__ csr,
                                                    const int* __restrict__ perm,
                                                    const float* __restrict__ W2,
                                                    const float* __restrict__ b2,
                                                    unsigned short* __restrict__ hh2_bf,
                                                    float* __restrict__ aggs2) {
    __shared__ f32x4 w2s[64];   // W2 row-major [16][16] as float4[64]
    __shared__ f32x4 b2s[4];
    const int tid = threadIdx.x;
    if (tid < 64) w2s[tid] = ((const f32x4*)W2)[tid];
    if (tid < 4)  b2s[tid] = ((const f32x4*)b2)[tid];
    __syncthreads();

    int t = blockIdx.x * 256 + tid;
    int node = perm[t >> 2];
    int l = t & 3;                      // feature quad: features 4l..4l+3
    if (node >= N_NODES) return;

    int2 re = row2[node];
    int p = re.x, e = re.y;
    const unsigned short* hb = hh_bf + (l << 2);
    f32x4 a0 = {0,0,0,0}, a1 = {0,0,0,0}, a2 = {0,0,0,0}, a3 = {0,0,0,0};
    for (; p < e; p += 4) {
        int4 s = *(const int4*)(csr + p);          // aligned: starts are mult-of-4
        ushort4 g0 = *(const ushort4*)(hb + (s.x << 4));
        ushort4 g1 = *(const ushort4*)(hb + (s.y << 4));
        ushort4 g2 = *(const ushort4*)(hb + (s.z << 4));
        ushort4 g3 = *(const ushort4*)(hb + (s.w << 4));
        a0.x += bf2f(g0.x); a0.y += bf2f(g0.y); a0.z += bf2f(g0.z); a0.w += bf2f(g0.w);
        a1.x += bf2f(g1.x); a1.y += bf2f(g1.y); a1.z += bf2f(g1.z); a1.w += bf2f(g1.w);
        a2.x += bf2f(g2.x); a2.y += bf2f(g2.y); a2.z += bf2f(g2.z); a2.w += bf2f(g2.w);
        a3.x += bf2f(g3.x); a3.y += bf2f(g3.y); a3.z += bf2f(g3.z); a3.w += bf2f(g3.w);
    }
    f32x4 a = (a0 + a1) + (a2 + a3);
    float dv = dinv[node];
    f32x4 base = *(const f32x4*)(aggs1 + ((size_t)node << 4) + (l << 2));
    float v[4];
    #pragma unroll
    for (int c = 0; c < 4; ++c) v[c] = fmaxf(base[c] + dv * a[c], 0.f);  // relu(h1)

    // h2[4l+d] = sum_k v_node[k] * W2[k][4l+d]; v[c] lives on lane k>>2 at c=k&3
    f32x4 h2 = {0.f, 0.f, 0.f, 0.f};
    #pragma unroll
    for (int k = 0; k < 16; ++k) {
        float vk = __shfl(v[k & 3], k >> 2, 4);
        f32x4 w = w2s[k * 4 + l];
        h2.x += vk * w.x; h2.y += vk * w.y; h2.z += vk * w.z; h2.w += vk * w.w;
    }
    f32x4 bb = b2s[l];
    ushort4 hs;
    f32x4 ag;
    float hv0 = h2.x * dv; hs.x = f2bf_rne(hv0); ag.x = hv0 * dv + bb.x;
    float hv1 = h2.y * dv; hs.y = f2bf_rne(hv1); ag.y = hv1 * dv + bb.y;
    float hv2 = h2.z * dv; hs.z = f2bf_rne(hv2); ag.z = hv2 * dv + bb.z;
    float hv3 = h2.w * dv; hs.w = f2bf_rne(hv3); ag.w = hv3 * dv + bb.w;
    size_t o = ((size_t)node << 4) + (l << 2);
    *(ushort4*)(hh2_bf + o) = hs;
    *(f32x4*)(aggs2 + o) = ag;
}

// ---------------------------------------------------------------------------
// K5: pull2 + log_softmax fused. Same 4-lane gather structure (degree-sorted).
__global__ __launch_bounds__(256) void pull2_kernel(const unsigned short* __restrict__ hh2_bf,
                                                    const float* __restrict__ aggs2,
                                                    const float* __restrict__ dinv,
                                                    const int2* __restrict__ row2,
                                                    const int* __restrict__ csr,
                                                    const int* __restrict__ perm,
                                                    float* __restrict__ out) {
    int t = blockIdx.x * 256 + threadIdx.x;
    int node = perm[t >> 2];
    int l = t & 3;
    if (node >= N_NODES) return;

    int2 re = row2[node];
    int p = re.x, e = re.y;
    const unsigned short* hb = hh2_bf + (l << 2);
    f32x4 a0 = {0,0,0,0}, a1 = {0,0,0,0}, a2 = {0,0,0,0}, a3 = {0,0,0,0};
    for (; p < e; p += 4) {
        int4 s = *(const int4*)(csr + p);
        ushort4 g0 = *(const ushort4*)(hb + (s.x << 4));
        ushort4 g1 = *(const ushort4*)(hb + (s.y << 4));
        ushort4 g2 = *(const ushort4*)(hb + (s.z << 4));
        ushort4 g3 = *(const ushort4*)(hb + (s.w << 4));
        a0.x += bf2f(g0.x); a0.y += bf2f(g0.y); a0.z += bf2f(g0.z); a0.w += bf2f(g0.w);
        a1.x += bf2f(g1.x); a1.y += bf2f(g1.y); a1.z += bf2f(g1.z); a1.w += bf2f(g1.w);
        a2.x += bf2f(g2.x); a2.y += bf2f(g2.y); a2.z += bf2f(g2.z); a2.w += bf2f(g2.w);
        a3.x += bf2f(g3.x); a3.y += bf2f(g3.y); a3.z += bf2f(g3.z); a3.w += bf2f(g3.w);
    }
    f32x4 a = (a0 + a1) + (a2 + a3);
    float dv = dinv[node];
    f32x4 base = *(const f32x4*)(aggs2 + ((size_t)node << 4) + (l << 2));
    f32x4 o4;
    o4.x = base.x + dv * a.x; o4.y = base.y + dv * a.y;
    o4.z = base.z + dv * a.z; o4.w = base.w + dv * a.w;

    // log_softmax over the 16 features spread across the 4-lane group
    float m = fmaxf(fmaxf(o4.x, o4.y), fmaxf(o4.z, o4.w));
    m = fmaxf(m, __shfl_xor(m, 1));
    m = fmaxf(m, __shfl_xor(m, 2));
    float s = expf(o4.x - m) + expf(o4.y - m) + expf(o4.z - m) + expf(o4.w - m);
    s += __shfl_xor(s, 1);
    s += __shfl_xor(s, 2);
    float ls = m + logf(s);
    f32x4 r;
    r.x = o4.x - ls; r.y = o4.y - ls; r.z = o4.z - ls; r.w = o4.w - ls;
    *(f32x4*)(out + ((size_t)node << 4) + (l << 2)) = r;
}

// ---------------------------------------------------------------------------
extern "C" void kernel_launch(void* const* d_in, const int* in_sizes, int n_in,
                              void* d_out, int out_size, void* d_ws, size_t ws_size,
                              hipStream_t stream) {
    const float* x    = (const float*)d_in[0];
    const float* W1   = (const float*)d_in[1];
    const float* b1   = (const float*)d_in[2];
    const float* W2   = (const float*)d_in[3];
    const float* b2   = (const float*)d_in[4];
    const int*   ei   = (const int*)d_in[5];
    const int*   src  = ei;             // edge_index[0]
    const int*   dst  = ei + N_EDGES;   // edge_index[1]
    float* out = (float*)d_out;

    // workspace layout (4-byte words); total ~37 MB
    constexpr size_t SLOTS    = (size_t)NBKT * CAP;          // 4,003,840
    constexpr size_t OFF_DINV = 512;
    constexpr size_t OFF_ROW2 = 512 + (size_t)NPAD;          // int2[N] = 2*NPAD words
    constexpr size_t OFF_PERM = 512 + 3 * (size_t)NPAD;      // [NBKT*NPB]
    constexpr size_t OFF_CSR  = 512 + 4 * (size_t)NPAD;
    constexpr size_t OFF_HH   = OFF_CSR + SLOTS;             // (N+1)*16 bf16
    constexpr size_t OFF_AG1  = OFF_HH + 800512;
    constexpr size_t OFF_HH2  = OFF_AG1 + 1600000;
    constexpr size_t OFF_AG2  = OFF_HH2 + 800512;
    constexpr size_t OFF_W1T  = OFF_AG2 + 1600000;

    int*   wsi  = (int*)d_ws;
    float* wsf  = (float*)d_ws;
    int*   gcur  = wsi;
    float* dinv  = wsf + OFF_DINV;
    int2*  row2  = (int2*)(wsi + OFF_ROW2);
    int*   perm  = wsi + OFF_PERM;
    int*   csr   = wsi + OFF_CSR;
    unsigned int* binned = (unsigned int*)csr;   // shared: staged per-bucket in LDS
    unsigned short* hh_bf  = (unsigned short*)(wsi + OFF_HH);
    float*          aggs1  = wsf + OFF_AG1;
    unsigned short* hh2_bf = (unsigned short*)(wsi + OFF_HH2);
    float*          aggs2  = wsf + OFF_AG2;
    unsigned short* w1t    = (unsigned short*)(wsi + OFF_W1T);

    const int MB  = (N_NODES + 63) / 64;         // 1563 (MFMA gemm blocks)
    const int GB4 = (NBKT * NPB * 4) / 256;      // 1564 (pull blocks, 4 lanes/node)

    prep_kernel       <<<32, 256, 0, stream>>>(W1, w1t, gcur, hh_bf, hh2_bf);
    bin_scatter_kernel<<<SBLK, 1024, 0, stream>>>(src, dst, gcur, binned);
    csr_bucket_kernel <<<NBKT, 1024, 0, stream>>>(binned, gcur, row2, csr, dinv, perm);
    gemm1_kernel      <<<MB, 256, 0, stream>>>(x, w1t, b1, dinv, hh_bf, aggs1);
    pull1_kernel      <<<GB4, 256, 0, stream>>>(hh_bf, aggs1, dinv, row2, csr, perm, W2, b2, hh2_bf, aggs2);
    pull2_kernel      <<<GB4, 256, 0, stream>>>(hh2_bf, aggs2, dinv, row2, csr, perm, out);
}

// Round 5
// 437.828 us; speedup vs baseline: 1.0551x; 1.0306x over previous
//
#include <hip/hip_runtime.h>
#include <hip/hip_bf16.h>
#include <math.h>

// Problem constants (fixed by the reference file).
constexpr int N_NODES = 100000;
constexpr int N_EDGES = 3200000;
constexpr int F_IN    = 512;
constexpr int HID     = 16;   // HIDDEN == N_CLASSES == 16

constexpr int NPAD = 100352;  // N_NODES rounded up (words)

// Binning parameters: bucket = dst >> 8 (256 nodes/bucket)
constexpr int B_BITS = 8;
constexpr int NPB    = 1 << B_BITS;                    // 256 nodes per bucket
constexpr int NBKT   = (N_NODES + NPB - 1) / NPB;      // 391 buckets
constexpr int SBLK   = 400;                            // scatter blocks
constexpr int CHUNK  = N_EDGES / SBLK;                 // 8000 edges/block (exact)
// Capacity-slotted buckets: mean 8192 edges + pad-to-4 (~384 mean), sd ~90.
constexpr int CAP    = 10240;                          // slots per bucket (mult of 4)

typedef float f32x4 __attribute__((ext_vector_type(4)));
typedef short bfrag8 __attribute__((ext_vector_type(8)));   // 8 bf16 (4 VGPRs)

__device__ __forceinline__ unsigned short f2bf_rne(float f) {
    unsigned int u = __float_as_uint(f);
    u += 0x7FFFu + ((u >> 16) & 1u);   // round-to-nearest-even
    return (unsigned short)(u >> 16);
}
__device__ __forceinline__ float bf2f(unsigned short u) {
    return __uint_as_float((unsigned int)u << 16);
}

// ---------------------------------------------------------------------------
// K0: prep — W1 transpose->bf16, gcur init to slotted bases, sentinel rows = 0.
__global__ __launch_bounds__(256) void prep_kernel(const float* __restrict__ W1,
                                                   unsigned short* __restrict__ w1t,
                                                   int* __restrict__ gcur,
                                                   unsigned short* __restrict__ hh_bf,
                                                   unsigned short* __restrict__ hh2_bf) {
    int i = blockIdx.x * 256 + threadIdx.x;
    if (i < F_IN * HID) {
        int k = i >> 4, n = i & 15;
        w1t[n * F_IN + k] = f2bf_rne(W1[i]);
    }
    if (i < NBKT) gcur[i] = i * CAP;
    if (i < 16) {                       // sentinel row N_NODES reads as zero
        hh_bf [N_NODES * 16 + i] = 0;
        hh2_bf[N_NODES * 16 + i] = 0;
    }
}

// ---------------------------------------------------------------------------
// K1: scatter edges into capacity-slotted bucket array (LDS-staged: src/dst
// read from HBM exactly once). Packed as (local_dst<<24 | src).
__global__ __launch_bounds__(1024) void bin_scatter_kernel(const int* __restrict__ src,
                                                           const int* __restrict__ dst,
                                                           int* __restrict__ gcur,
                                                           unsigned int* __restrict__ binned) {
    __shared__ int sdst[CHUNK];
    __shared__ int ssrc[CHUNK];
    __shared__ int cnt[NBKT];
    __shared__ int cur[NBKT];
    const int tid = threadIdx.x;
    for (int t = tid; t < NBKT; t += 1024) cnt[t] = 0;
    const int base = blockIdx.x * CHUNK;
    for (int i = tid; i < CHUNK; i += 1024) {
        sdst[i] = dst[base + i];
        ssrc[i] = src[base + i];
    }
    __syncthreads();
    for (int i = tid; i < CHUNK; i += 1024)
        atomicAdd(&cnt[sdst[i] >> B_BITS], 1);
    __syncthreads();
    for (int t = tid; t < NBKT; t += 1024)
        cur[t] = cnt[t] ? atomicAdd(&gcur[t], cnt[t]) : 0;
    __syncthreads();
    for (int i = tid; i < CHUNK; i += 1024) {
        int d = sdst[i];
        int b = d >> B_BITS;
        int pos = atomicAdd(&cur[b], 1);
        binned[pos] = ((unsigned)(d & (NPB - 1)) << 24) | (unsigned)ssrc[i];
    }
}

// ---------------------------------------------------------------------------
// K2: one block per bucket: LDS CSR build with per-node 4-alignment padding
// (sentinel src = N_NODES fills pad slots -> pull loops are tail-free and
// csr starts are 16B aligned for int4 loads). Emits row2/dinv.
__global__ __launch_bounds__(1024) void csr_bucket_kernel(const unsigned int* __restrict__ binned,
                                                          const int* __restrict__ gcur,
                                                          int2* __restrict__ row2,
                                                          int* __restrict__ csr,
                                                          float* __restrict__ dinv) {
    __shared__ unsigned int eb[CAP];   // 40 KB
    __shared__ int deg[NPB];
    __shared__ int pre[NPB];
    __shared__ int cur[NPB];
    const int tid = threadIdx.x;
    const int b = blockIdx.x;
    const int e0 = b * CAP;
    int ne = gcur[b] - e0;
    if (ne > CAP) ne = CAP;            // safety (statistically impossible)
    if (ne < 0) ne = 0;

    if (tid < NPB) deg[tid] = 0;
    for (int i = tid; i < ne; i += 1024) eb[i] = binned[e0 + i];
    __syncthreads();
    for (int i = tid; i < ne; i += 1024)
        atomicAdd(&deg[eb[i] >> 24], 1);
    __syncthreads();
    if (tid < NPB) pre[tid] = (deg[tid] + 3) & ~3;   // padded degree (mult 4)
    __syncthreads();
    for (int off = 1; off < NPB; off <<= 1) {
        int v = 0;
        if (tid < NPB && tid >= off) v = pre[tid - off];
        __syncthreads();
        if (tid < NPB) pre[tid] += v;
        __syncthreads();
    }
    if (tid < NPB) {
        int excl = (tid == 0) ? 0 : pre[tid - 1];
        int start = e0 + excl;
        cur[tid] = start;
        int node = b * NPB + tid;
        if (node < N_NODES) {
            int pd = (deg[tid] + 3) & ~3;
            row2[node] = make_int2(start, start + pd);
            dinv[node] = rsqrtf((float)deg[tid] + 1.0f);
        }
    }
    __syncthreads();
    for (int i = tid; i < ne; i += 1024) {
        unsigned int v = eb[i];
        int pos = atomicAdd(&cur[v >> 24], 1);
        csr[pos] = (int)(v & 0xFFFFFFu);
    }
    // sentinel fill of pad slots (disjoint range from the scatter above)
    if (tid < NPB) {
        int node = b * NPB + tid;
        if (node < N_NODES) {
            int d = deg[tid];
            int pdl = (d + 3) & ~3;
            int s = e0 + ((tid == 0) ? 0 : pre[tid - 1]) + d;
            for (int q = d; q < pdl; ++q) csr[s++] = N_NODES;
        }
    }
}

// ---------------------------------------------------------------------------
// K3: GEMM1 via MFMA bf16, NO LDS, NO barrier. fp32->bf16 via paired
// __float22bfloat162_rn (v_cvt_pk_bf16_f32: 1 instr / 2 elems; identical
// RNE bits to the bit-twiddle) -> memory-bound on x.
__global__ __launch_bounds__(256) void gemm1_kernel(const float* __restrict__ x,
                                                    const unsigned short* __restrict__ w1t,
                                                    const float* __restrict__ b1,
                                                    const float* __restrict__ dinv,
                                                    unsigned short* __restrict__ hh_bf,
                                                    float* __restrict__ aggs1) {
    const int tid  = threadIdx.x;
    const int lane = tid & 63;
    const int wv   = tid >> 6;
    const int m    = lane & 15;
    const int quad = lane >> 4;
    const int node0 = blockIdx.x * 64 + wv * 16;   // this wave's 16-node tile

    int gm = node0 + m; if (gm >= N_NODES) gm = N_NODES - 1;  // clamp loads
    const float* arow = x + (size_t)gm * F_IN + quad * 8;

    // preload all 16 B-frags (16 KB table, L2-hot)
    bfrag8 bfr[16];
    const unsigned short* wbase = w1t + m * F_IN + quad * 8;
    #pragma unroll
    for (int t = 0; t < 16; ++t)
        bfr[t] = *(const bfrag8*)(wbase + t * 32);

    f32x4 acc = {0.f, 0.f, 0.f, 0.f};
    #pragma unroll 4
    for (int t = 0; t < 16; ++t) {
        float4 lo = *(const float4*)(arow + t * 32);
        float4 hi = *(const float4*)(arow + t * 32 + 4);
        union { bfrag8 fr; __hip_bfloat162 h2[4]; } u;
        u.h2[0] = __float22bfloat162_rn(float2{lo.x, lo.y});
        u.h2[1] = __float22bfloat162_rn(float2{lo.z, lo.w});
        u.h2[2] = __float22bfloat162_rn(float2{hi.x, hi.y});
        u.h2[3] = __float22bfloat162_rn(float2{hi.z, hi.w});
        acc = __builtin_amdgcn_mfma_f32_16x16x32_bf16(u.fr, bfr[t], acc, 0, 0, 0);
    }

    // epilogue: D[row=quad*4+r][col=m] (verified mapping)
    const float b1j = b1[m];
    #pragma unroll
    for (int r = 0; r < 4; ++r) {
        int gn = node0 + quad * 4 + r;
        if (gn < N_NODES) {
            float dv = dinv[gn];
            float hv = acc[r] * dv;
            size_t o = (size_t)gn * 16 + m;
            hh_bf[o] = f2bf_rne(hv);
            aggs1[o] = hv * dv + b1j;
        }
    }
}

// ---------------------------------------------------------------------------
// K4: pull1 + relu + layer2 fused. 4 lanes per node, each owning 4 features.
// Main loop manually unrolled 2x (8 edges/iter: 2 int4 csr loads + 8 ushort4
// gathers in flight per lane) with a single 4-edge remainder — doubles MLP
// at unchanged wave count (R2 lesson: never trade TLP away).
__global__ __launch_bounds__(256) void pull1_kernel(const unsigned short* __restrict__ hh_bf,
                                                    const float* __restrict__ aggs1,
                                                    const float* __restrict__ dinv,
                                                    const int2* __restrict__ row2,
                                                    const int* __restrict__ csr,
                                                    const float* __restrict__ W2,
                                                    const float* __restrict__ b2,
                                                    unsigned short* __restrict__ hh2_bf,
                                                    float* __restrict__ aggs2) {
    __shared__ f32x4 w2s[64];   // W2 row-major [16][16] as float4[64]
    __shared__ f32x4 b2s[4];
    const int tid = threadIdx.x;
    if (tid < 64) w2s[tid] = ((const f32x4*)W2)[tid];
    if (tid < 4)  b2s[tid] = ((const f32x4*)b2)[tid];
    __syncthreads();

    int t = blockIdx.x * 256 + tid;
    int node = t >> 2;
    int l = t & 3;                      // feature quad: features 4l..4l+3
    if (node >= N_NODES) return;

    int2 re = row2[node];
    int p = re.x, e = re.y;
    const unsigned short* hb = hh_bf + (l << 2);
    f32x4 a0 = {0,0,0,0}, a1 = {0,0,0,0}, a2 = {0,0,0,0}, a3 = {0,0,0,0};
    f32x4 a4 = {0,0,0,0}, a5 = {0,0,0,0}, a6 = {0,0,0,0}, a7 = {0,0,0,0};
    for (; p + 8 <= e; p += 8) {
        int4 sA = *(const int4*)(csr + p);
        int4 sB = *(const int4*)(csr + p + 4);
        ushort4 g0 = *(const ushort4*)(hb + (sA.x << 4));
        ushort4 g1 = *(const ushort4*)(hb + (sA.y << 4));
        ushort4 g2 = *(const ushort4*)(hb + (sA.z << 4));
        ushort4 g3 = *(const ushort4*)(hb + (sA.w << 4));
        ushort4 g4 = *(const ushort4*)(hb + (sB.x << 4));
        ushort4 g5 = *(const ushort4*)(hb + (sB.y << 4));
        ushort4 g6 = *(const ushort4*)(hb + (sB.z << 4));
        ushort4 g7 = *(const ushort4*)(hb + (sB.w << 4));
        a0.x += bf2f(g0.x); a0.y += bf2f(g0.y); a0.z += bf2f(g0.z); a0.w += bf2f(g0.w);
        a1.x += bf2f(g1.x); a1.y += bf2f(g1.y); a1.z += bf2f(g1.z); a1.w += bf2f(g1.w);
        a2.x += bf2f(g2.x); a2.y += bf2f(g2.y); a2.z += bf2f(g2.z); a2.w += bf2f(g2.w);
        a3.x += bf2f(g3.x); a3.y += bf2f(g3.y); a3.z += bf2f(g3.z); a3.w += bf2f(g3.w);
        a4.x += bf2f(g4.x); a4.y += bf2f(g4.y); a4.z += bf2f(g4.z); a4.w += bf2f(g4.w);
        a5.x += bf2f(g5.x); a5.y += bf2f(g5.y); a5.z += bf2f(g5.z); a5.w += bf2f(g5.w);
        a6.x += bf2f(g6.x); a6.y += bf2f(g6.y); a6.z += bf2f(g6.z); a6.w += bf2f(g6.w);
        a7.x += bf2f(g7.x); a7.y += bf2f(g7.y); a7.z += bf2f(g7.z); a7.w += bf2f(g7.w);
    }
    if (p < e) {                        // exactly one 4-edge remainder possible
        int4 s = *(const int4*)(csr + p);
        ushort4 g0 = *(const ushort4*)(hb + (s.x << 4));
        ushort4 g1 = *(const ushort4*)(hb + (s.y << 4));
        ushort4 g2 = *(const ushort4*)(hb + (s.z << 4));
        ushort4 g3 = *(const ushort4*)(hb + (s.w << 4));
        a0.x += bf2f(g0.x); a0.y += bf2f(g0.y); a0.z += bf2f(g0.z); a0.w += bf2f(g0.w);
        a1.x += bf2f(g1.x); a1.y += bf2f(g1.y); a1.z += bf2f(g1.z); a1.w += bf2f(g1.w);
        a2.x += bf2f(g2.x); a2.y += bf2f(g2.y); a2.z += bf2f(g2.z); a2.w += bf2f(g2.w);
        a3.x += bf2f(g3.x); a3.y += bf2f(g3.y); a3.z += bf2f(g3.z); a3.w += bf2f(g3.w);
    }
    f32x4 a = ((a0 + a1) + (a2 + a3)) + ((a4 + a5) + (a6 + a7));
    float dv = dinv[node];
    f32x4 base = *(const f32x4*)(aggs1 + ((size_t)node << 4) + (l << 2));
    float v[4];
    #pragma unroll
    for (int c = 0; c < 4; ++c) v[c] = fmaxf(base[c] + dv * a[c], 0.f);  // relu(h1)

    // h2[4l+d] = sum_k v_node[k] * W2[k][4l+d]; v[c] lives on lane k>>2 at c=k&3
    f32x4 h2 = {0.f, 0.f, 0.f, 0.f};
    #pragma unroll
    for (int k = 0; k < 16; ++k) {
        float vk = __shfl(v[k & 3], k >> 2, 4);
        f32x4 w = w2s[k * 4 + l];
        h2.x += vk * w.x; h2.y += vk * w.y; h2.z += vk * w.z; h2.w += vk * w.w;
    }
    f32x4 bb = b2s[l];
    ushort4 hs;
    f32x4 ag;
    float hv0 = h2.x * dv; hs.x = f2bf_rne(hv0); ag.x = hv0 * dv + bb.x;
    float hv1 = h2.y * dv; hs.y = f2bf_rne(hv1); ag.y = hv1 * dv + bb.y;
    float hv2 = h2.z * dv; hs.z = f2bf_rne(hv2); ag.z = hv2 * dv + bb.z;
    float hv3 = h2.w * dv; hs.w = f2bf_rne(hv3); ag.w = hv3 * dv + bb.w;
    size_t o = ((size_t)node << 4) + (l << 2);
    *(ushort4*)(hh2_bf + o) = hs;
    *(f32x4*)(aggs2 + o) = ag;
}

// ---------------------------------------------------------------------------
// K5: pull2 + log_softmax fused. Same unrolled 4-lane gather structure.
__global__ __launch_bounds__(256) void pull2_kernel(const unsigned short* __restrict__ hh2_bf,
                                                    const float* __restrict__ aggs2,
                                                    const float* __restrict__ dinv,
                                                    const int2* __restrict__ row2,
                                                    const int* __restrict__ csr,
                                                    float* __restrict__ out) {
    int t = blockIdx.x * 256 + threadIdx.x;
    int node = t >> 2;
    int l = t & 3;
    if (node >= N_NODES) return;

    int2 re = row2[node];
    int p = re.x, e = re.y;
    const unsigned short* hb = hh2_bf + (l << 2);
    f32x4 a0 = {0,0,0,0}, a1 = {0,0,0,0}, a2 = {0,0,0,0}, a3 = {0,0,0,0};
    f32x4 a4 = {0,0,0,0}, a5 = {0,0,0,0}, a6 = {0,0,0,0}, a7 = {0,0,0,0};
    for (; p + 8 <= e; p += 8) {
        int4 sA = *(const int4*)(csr + p);
        int4 sB = *(const int4*)(csr + p + 4);
        ushort4 g0 = *(const ushort4*)(hb + (sA.x << 4));
        ushort4 g1 = *(const ushort4*)(hb + (sA.y << 4));
        ushort4 g2 = *(const ushort4*)(hb + (sA.z << 4));
        ushort4 g3 = *(const ushort4*)(hb + (sA.w << 4));
        ushort4 g4 = *(const ushort4*)(hb + (sB.x << 4));
        ushort4 g5 = *(const ushort4*)(hb + (sB.y << 4));
        ushort4 g6 = *(const ushort4*)(hb + (sB.z << 4));
        ushort4 g7 = *(const ushort4*)(hb + (sB.w << 4));
        a0.x += bf2f(g0.x); a0.y += bf2f(g0.y); a0.z += bf2f(g0.z); a0.w += bf2f(g0.w);
        a1.x += bf2f(g1.x); a1.y += bf2f(g1.y); a1.z += bf2f(g1.z); a1.w += bf2f(g1.w);
        a2.x += bf2f(g2.x); a2.y += bf2f(g2.y); a2.z += bf2f(g2.z); a2.w += bf2f(g2.w);
        a3.x += bf2f(g3.x); a3.y += bf2f(g3.y); a3.z += bf2f(g3.z); a3.w += bf2f(g3.w);
        a4.x += bf2f(g4.x); a4.y += bf2f(g4.y); a4.z += bf2f(g4.z); a4.w += bf2f(g4.w);
        a5.x += bf2f(g5.x); a5.y += bf2f(g5.y); a5.z += bf2f(g5.z); a5.w += bf2f(g5.w);
        a6.x += bf2f(g6.x); a6.y += bf2f(g6.y); a6.z += bf2f(g6.z); a6.w += bf2f(g6.w);
        a7.x += bf2f(g7.x); a7.y += bf2f(g7.y); a7.z += bf2f(g7.z); a7.w += bf2f(g7.w);
    }
    if (p < e) {
        int4 s = *(const int4*)(csr + p);
        ushort4 g0 = *(const ushort4*)(hb + (s.x << 4));
        ushort4 g1 = *(const ushort4*)(hb + (s.y << 4));
        ushort4 g2 = *(const ushort4*)(hb + (s.z << 4));
        ushort4 g3 = *(const ushort4*)(hb + (s.w << 4));
        a0.x += bf2f(g0.x); a0.y += bf2f(g0.y); a0.z += bf2f(g0.z); a0.w += bf2f(g0.w);
        a1.x += bf2f(g1.x); a1.y += bf2f(g1.y); a1.z += bf2f(g1.z); a1.w += bf2f(g1.w);
        a2.x += bf2f(g2.x); a2.y += bf2f(g2.y); a2.z += bf2f(g2.z); a2.w += bf2f(g2.w);
        a3.x += bf2f(g3.x); a3.y += bf2f(g3.y); a3.z += bf2f(g3.z); a3.w += bf2f(g3.w);
    }
    f32x4 a = ((a0 + a1) + (a2 + a3)) + ((a4 + a5) + (a6 + a7));
    float dv = dinv[node];
    f32x4 base = *(const f32x4*)(aggs2 + ((size_t)node << 4) + (l << 2));
    f32x4 o4;
    o4.x = base.x + dv * a.x; o4.y = base.y + dv * a.y;
    o4.z = base.z + dv * a.z; o4.w = base.w + dv * a.w;

    // log_softmax over the 16 features spread across the 4-lane group
    float m = fmaxf(fmaxf(o4.x, o4.y), fmaxf(o4.z, o4.w));
    m = fmaxf(m, __shfl_xor(m, 1));
    m = fmaxf(m, __shfl_xor(m, 2));
    float s = expf(o4.x - m) + expf(o4.y - m) + expf(o4.z - m) + expf(o4.w - m);
    s += __shfl_xor(s, 1);
    s += __shfl_xor(s, 2);
    float ls = m + logf(s);
    f32x4 r;
    r.x = o4.x - ls; r.y = o4.y - ls; r.z = o4.z - ls; r.w = o4.w - ls;
    *(f32x4*)(out + ((size_t)node << 4) + (l << 2)) = r;
}

// ---------------------------------------------------------------------------
extern "C" void kernel_launch(void* const* d_in, const int* in_sizes, int n_in,
                              void* d_out, int out_size, void* d_ws, size_t ws_size,
                              hipStream_t stream) {
    const float* x    = (const float*)d_in[0];
    const float* W1   = (const float*)d_in[1];
    const float* b1   = (const float*)d_in[2];
    const float* W2   = (const float*)d_in[3];
    const float* b2   = (const float*)d_in[4];
    const int*   ei   = (const int*)d_in[5];
    const int*   src  = ei;             // edge_index[0]
    const int*   dst  = ei + N_EDGES;   // edge_index[1]
    float* out = (float*)d_out;

    // workspace layout (4-byte words); total ~37 MB
    constexpr size_t SLOTS    = (size_t)NBKT * CAP;          // 4,003,840
    constexpr size_t OFF_DINV = 512;
    constexpr size_t OFF_ROW2 = 512 + (size_t)NPAD;          // int2[N] = 2*NPAD words
    constexpr size_t OFF_CSR  = 512 + 3 * (size_t)NPAD;
    constexpr size_t OFF_HH   = OFF_CSR + SLOTS;             // (N+1)*16 bf16
    constexpr size_t OFF_AG1  = OFF_HH + 800512;
    constexpr size_t OFF_HH2  = OFF_AG1 + 1600000;
    constexpr size_t OFF_AG2  = OFF_HH2 + 800512;
    constexpr size_t OFF_W1T  = OFF_AG2 + 1600000;

    int*   wsi  = (int*)d_ws;
    float* wsf  = (float*)d_ws;
    int*   gcur  = wsi;
    float* dinv  = wsf + OFF_DINV;
    int2*  row2  = (int2*)(wsi + OFF_ROW2);
    int*   csr   = wsi + OFF_CSR;
    unsigned int* binned = (unsigned int*)csr;   // shared: staged per-bucket in LDS
    unsigned short* hh_bf  = (unsigned short*)(wsi + OFF_HH);
    float*          aggs1  = wsf + OFF_AG1;
    unsigned short* hh2_bf = (unsigned short*)(wsi + OFF_HH2);
    float*          aggs2  = wsf + OFF_AG2;
    unsigned short* w1t    = (unsigned short*)(wsi + OFF_W1T);

    const int MB  = (N_NODES + 63) / 64;         // 1563 (MFMA gemm blocks)
    const int GB4 = (N_NODES * 4 + 255) / 256;   // 1563 (pull blocks, 4 lanes/node)

    prep_kernel       <<<32, 256, 0, stream>>>(W1, w1t, gcur, hh_bf, hh2_bf);
    bin_scatter_kernel<<<SBLK, 1024, 0, stream>>>(src, dst, gcur, binned);
    csr_bucket_kernel <<<NBKT, 1024, 0, stream>>>(binned, gcur, row2, csr, dinv);
    gemm1_kernel      <<<MB, 256, 0, stream>>>(x, w1t, b1, dinv, hh_bf, aggs1);
    pull1_kernel      <<<GB4, 256, 0, stream>>>(hh_bf, aggs1, dinv, row2, csr, W2, b2, hh2_bf, aggs2);
    pull2_kernel      <<<GB4, 256, 0, stream>>>(hh2_bf, aggs2, dinv, row2, csr, out);
}